// Round 13
// baseline (1284.344 us; speedup 1.0000x reference)
//
#include <hip/hip_runtime.h>
#include <hip/hip_bf16.h>

using bf16 = __hip_bfloat16;
typedef __attribute__((ext_vector_type(8))) short short8;
typedef __attribute__((ext_vector_type(4))) float f32x4;

#define GAS(p) ((const __attribute__((address_space(1))) unsigned int*)(p))
#define LAS(p) ((__attribute__((address_space(3))) unsigned int*)(p))

// ---------------- cast f32 -> bf16 (vectorized) ----------------
__global__ __launch_bounds__(256)
void cast_f32_to_bf16(const float* __restrict__ in, bf16* __restrict__ out, int n) {
  const int stride = gridDim.x * blockDim.x * 4;
  for (int i = (blockIdx.x * blockDim.x + threadIdx.x) * 4; i < n; i += stride) {
    float4 v = *reinterpret_cast<const float4*>(in + i);
    bf16 b0 = __float2bfloat16(v.x);
    bf16 b1 = __float2bfloat16(v.y);
    bf16 b2 = __float2bfloat16(v.z);
    bf16 b3 = __float2bfloat16(v.w);
    ushort4 p;
    p.x = *reinterpret_cast<unsigned short*>(&b0);
    p.y = *reinterpret_cast<unsigned short*>(&b1);
    p.z = *reinterpret_cast<unsigned short*>(&b2);
    p.w = *reinterpret_cast<unsigned short*>(&b3);
    *reinterpret_cast<ushort4*>(out + i) = p;
  }
}

// ========== 128x256 NT GEMM, 2 blocks/CU (TLP-overlap structure) ==========
// C[M,N] = A[M,K]*B[N,K]^T.  512 thr (8 waves, 2M x 4N), wave-tile 64x64
// (acc = 64 VGPR -> ~115 total, fits __launch_bounds__(512,4) = 128 cap =
// 2 blocks/CU).  Two co-resident blocks have INDEPENDENT barrier domains:
// block A's MFMA phase overlaps block B's LDS-read/stage phase — the
// implicit wave-level overlap (m97/m114 mechanism) that the 1-block/CU
// 256^2 tile could never get.
// LDS: 3 bufs x 24KB (A 8KB [128r][64B] + B 16KB [256r][64B]); BK=32.
// Staging: 3 gload_lds calls/tile (A 1, B 2), dest linear (t*16).
// Ledger: body t top = vmcnt(3) [in flight: STG(t)=3 old + STG(t+1)=3 new;
// wait to <=3 drains STG(t) exactly] + barrier + fence.  Stage t+2 into
// buf[(t+2)%3]: distinct from buf[t%3] (reading now) and buf[(t+1)%3];
// its last reads (body t-1) completed before this body's barrier -> WAR ok.
// Frag reads conflict-free: row-stride 64B, 16 rows x 4 g4-slots -> 2
// lanes per b128 bank-quad (free 2-way).
template <typename OutT, bool KMASK>
__global__ __launch_bounds__(512, 4)
void gemm128x256(const bf16* __restrict__ A, const bf16* __restrict__ B,
                 OutT* __restrict__ C, int M, int N, int K,
                 const float* __restrict__ mu_q, const float* __restrict__ sigma_q,
                 const float* __restrict__ eps_q,
                 const float* __restrict__ mu_kv, const float* __restrict__ sigma_kv,
                 const float* __restrict__ eps_kv) {
  extern __shared__ char smem[];   // 3 x 24576: [A 8KB | B 16KB]

  // bijective XCD swizzle (gridDim.x % 8 == 0)
  const int nwg = gridDim.x;
  const int cpx = nwg >> 3;
  const int bid = blockIdx.x;
  const int swz = (bid & 7) * cpx + (bid >> 3);
  const int ntn = N >> 8;                    // 256-wide column tiles
  const int tm = swz / ntn, tn = swz % ntn;
  const int row0 = tm << 7, col0 = tn << 8;  // 128-row, 256-col tiles

  const int t = threadIdx.x;
  const int wave = t >> 6, lane = t & 63;
  const int wm = wave >> 2, wn = wave & 3;   // 2 x 4 wave grid, 64x64 each
  const int fl = lane & 15, g4 = lane >> 4;

  // ---- staging source: row = t>>2, k-elems (t&3)*8 ----
  const int srow = t >> 2;                   // 0..127
  const int skoff = (t & 3) * 8;
  const size_t aSrc  = (size_t)(row0 + srow) * K + skoff;
  const size_t bSrc0 = (size_t)(col0 + srow) * K + skoff;
  const size_t bSrc1 = (size_t)(col0 + 128 + srow) * K + skoff;
  const int t16 = t * 16;

  // ---- fragment read bases (bytes within a buf) ----
  const int aoff = (wm * 64 + fl) * 64 + g4 * 16;           // + m*1024
  const int boff = 8192 + (wn * 64 + fl) * 64 + g4 * 16;    // + n*1024

  f32x4 acc[4][4];
#pragma unroll
  for (int m = 0; m < 4; ++m)
#pragma unroll
    for (int n = 0; n < 4; ++n) acc[m][n] = (f32x4)0.f;

#define STG(buf_, kk_) do {                                                   \
    __builtin_amdgcn_global_load_lds(GAS(A + aSrc + (kk_)),                   \
        LAS(smem + (buf_) * 24576 + t16), 16, 0, 0);                          \
    __builtin_amdgcn_global_load_lds(GAS(B + bSrc0 + (kk_)),                  \
        LAS(smem + (buf_) * 24576 + 8192 + t16), 16, 0, 0);                   \
    __builtin_amdgcn_global_load_lds(GAS(B + bSrc1 + (kk_)),                  \
        LAS(smem + (buf_) * 24576 + 16384 + t16), 16, 0, 0);                  \
  } while (0)

  const int NT = K >> 5;                     // 128 K-tiles of 32

  // prologue: stage tiles 0,1
  STG(0, 0);
  STG(1, 32);

  int bufCur = 0;
  for (int tt = 0; tt < NT; ++tt) {
    // drain STG(tt) exactly (3 newest = STG(tt+1) stay in flight)
    asm volatile("s_waitcnt vmcnt(3)" ::: "memory");
    __builtin_amdgcn_s_barrier();
    asm volatile("" ::: "memory");

    const char* bu = smem + bufCur * 24576;
    short8 af[4], bf[4];
#pragma unroll
    for (int m = 0; m < 4; ++m)
      af[m] = *reinterpret_cast<const short8*>(bu + aoff + m * 1024);
#pragma unroll
    for (int n = 0; n < 4; ++n)
      bf[n] = *reinterpret_cast<const short8*>(bu + boff + n * 1024);

    // stage tile tt+2 into the third buffer (not read this body or next)
    const int bufNxt2 = (bufCur + 2 >= 3) ? (bufCur - 1) : (bufCur + 2);
    STG(bufNxt2, (tt + 2 < NT) ? ((size_t)(tt + 2) << 5) : 0);

    __builtin_amdgcn_s_setprio(1);
#pragma unroll
    for (int m = 0; m < 4; ++m)
#pragma unroll
      for (int n = 0; n < 4; ++n)
        acc[m][n] = __builtin_amdgcn_mfma_f32_16x16x32_bf16(af[m], bf[n],
                                                            acc[m][n], 0, 0, 0);
    __builtin_amdgcn_s_setprio(0);

    bufCur = (bufCur + 1 >= 3) ? 0 : (bufCur + 1);
  }
#undef STG

  asm volatile("s_waitcnt vmcnt(0)" ::: "memory");

  // ---- epilogue: 16x16 C/D layout col=lane&15, row=(lane>>4)*4+reg ----
  const int crow0 = row0 + wm * 64 + g4 * 4;
  const int ccol0 = col0 + wn * 64 + fl;
  float cscale[4];
  if constexpr (KMASK) {
#pragma unroll
    for (int n = 0; n < 4; ++n) {
      const int d = (ccol0 + n * 16) & 63;
      const float a = mu_q[d] + eps_q[d] * sigma_q[d];
      const float b = mu_kv[d] + eps_kv[d] * sigma_kv[d];
      cscale[n] = 0.125f / ((1.f + __expf(-a)) * (1.f + __expf(-b)));
    }
  }
#pragma unroll
  for (int m = 0; m < 4; ++m) {
#pragma unroll
    for (int n = 0; n < 4; ++n) {
      const int cc = ccol0 + n * 16;
#pragma unroll
      for (int r = 0; r < 4; ++r) {
        const int rr = crow0 + m * 16 + r;
        float v = acc[m][n][r];
        if constexpr (KMASK) v *= cscale[n];
        if constexpr (sizeof(OutT) == 2) {
          C[(size_t)rr * N + cc] = __float2bfloat16(v);
        } else {
          C[(size_t)rr * N + cc] = v;
        }
      }
    }
  }
}

// ---------------- per-token cross-head attention, MFMA ----------------
__global__ __launch_bounds__(256)
void attn_mfma(const bf16* __restrict__ Q, const bf16* __restrict__ K,
               const bf16* __restrict__ V,
               const float* __restrict__ mu_kv, const float* __restrict__ sigma_kv,
               const float* __restrict__ eps_kv,
               bf16* __restrict__ AO) {
  __shared__ bf16 Vt[64][72];
  __shared__ bf16 P[4][16][72];

  const int t = threadIdx.x;
  const int wave = t >> 6, lane = t & 63;
  const int fl = lane & 15, g4 = lane >> 4;
  const int kq = g4 * 8;
  const size_t base = (size_t)blockIdx.x * 4096;

#pragma unroll
  for (int rep = 0; rep < 2; ++rep) {
    const int idx = rep * 256 + t;
    const int g = idx & 63;
    const int d0 = (idx >> 6) * 8;
    short8 v8 = *reinterpret_cast<const short8*>(&V[base + (size_t)g * 64 + d0]);
#pragma unroll
    for (int j = 0; j < 8; ++j)
      *reinterpret_cast<short*>(&Vt[d0 + j][g]) = (short)v8[j];
  }

  short8 aq[2];
#pragma unroll
  for (int ks = 0; ks < 2; ++ks)
    aq[ks] = *reinterpret_cast<const short8*>(
        &Q[base + (size_t)(wave * 16 + fl) * 64 + ks * 32 + kq]);
  short8 bk[4][2];
#pragma unroll
  for (int n = 0; n < 4; ++n)
#pragma unroll
    for (int ks = 0; ks < 2; ++ks)
      bk[n][ks] = *reinterpret_cast<const short8*>(
          &K[base + (size_t)(n * 16 + fl) * 64 + ks * 32 + kq]);

  f32x4 sacc[4];
#pragma unroll
  for (int n = 0; n < 4; ++n) sacc[n] = (f32x4)0.f;
#pragma unroll
  for (int n = 0; n < 4; ++n)
#pragma unroll
    for (int ks = 0; ks < 2; ++ks)
      sacc[n] = __builtin_amdgcn_mfma_f32_16x16x32_bf16(aq[ks], bk[n][ks],
                                                        sacc[n], 0, 0, 0);

  float recip[4];
  float ex[4][4];
#pragma unroll
  for (int r = 0; r < 4; ++r) {
    float mx = fmaxf(fmaxf(sacc[0][r], sacc[1][r]), fmaxf(sacc[2][r], sacc[3][r]));
    mx = fmaxf(mx, __shfl_xor(mx, 1, 64));
    mx = fmaxf(mx, __shfl_xor(mx, 2, 64));
    mx = fmaxf(mx, __shfl_xor(mx, 4, 64));
    mx = fmaxf(mx, __shfl_xor(mx, 8, 64));
    float sum = 0.f;
#pragma unroll
    for (int n = 0; n < 4; ++n) {
      ex[n][r] = __expf(sacc[n][r] - mx);
      sum += ex[n][r];
    }
    sum += __shfl_xor(sum, 1, 64);
    sum += __shfl_xor(sum, 2, 64);
    sum += __shfl_xor(sum, 4, 64);
    sum += __shfl_xor(sum, 8, 64);
    recip[r] = 1.f / sum;
  }

#pragma unroll
  for (int n = 0; n < 4; ++n)
#pragma unroll
    for (int r = 0; r < 4; ++r)
      P[wave][g4 * 4 + r][n * 16 + fl] = __float2bfloat16(ex[n][r]);

  __syncthreads();

  short8 ap[2];
#pragma unroll
  for (int ks = 0; ks < 2; ++ks)
    ap[ks] = *reinterpret_cast<const short8*>(&P[wave][fl][ks * 32 + kq]);
  short8 bv[4][2];
#pragma unroll
  for (int n = 0; n < 4; ++n)
#pragma unroll
    for (int ks = 0; ks < 2; ++ks)
      bv[n][ks] = *reinterpret_cast<const short8*>(&Vt[n * 16 + fl][ks * 32 + kq]);

  f32x4 oacc[4];
#pragma unroll
  for (int n = 0; n < 4; ++n) oacc[n] = (f32x4)0.f;
#pragma unroll
  for (int n = 0; n < 4; ++n)
#pragma unroll
    for (int ks = 0; ks < 2; ++ks)
      oacc[n] = __builtin_amdgcn_mfma_f32_16x16x32_bf16(ap[ks], bv[n][ks],
                                                        oacc[n], 0, 0, 0);

  float mkvc[4];
#pragma unroll
  for (int n = 0; n < 4; ++n) {
    const int d = n * 16 + fl;
    mkvc[n] = 1.f / (1.f + __expf(-(mu_kv[d] + eps_kv[d] * sigma_kv[d])));
  }
#pragma unroll
  for (int n = 0; n < 4; ++n) {
    const int d = n * 16 + fl;
#pragma unroll
    for (int r = 0; r < 4; ++r) {
      const int h = wave * 16 + g4 * 4 + r;
      AO[base + (size_t)h * 64 + d] =
          __float2bfloat16(oacc[n][r] * recip[r] * mkvc[n]);
    }
  }
}

// ---------------- launch ----------------
extern "C" void kernel_launch(void* const* d_in, const int* in_sizes, int n_in,
                              void* d_out, int out_size, void* d_ws, size_t ws_size,
                              hipStream_t stream) {
  (void)in_sizes; (void)n_in; (void)out_size; (void)ws_size;
  const float* X        = (const float*)d_in[0];
  const float* Wq       = (const float*)d_in[1];
  const float* Wk       = (const float*)d_in[2];
  const float* Wv       = (const float*)d_in[3];
  const float* Wo       = (const float*)d_in[4];
  const float* mu_q     = (const float*)d_in[5];
  const float* sigma_q  = (const float*)d_in[6];
  const float* mu_kv    = (const float*)d_in[7];
  const float* sigma_kv = (const float*)d_in[8];
  const float* eps_q    = (const float*)d_in[9];
  const float* eps_kv   = (const float*)d_in[10];
  float* out = (float*)d_out;

  const int M = 8192, N = 4096, Kd = 4096;

  char* ws = (char*)d_ws;
  bf16* Xb = (bf16*)(ws);                              // 64 MiB (reused as AO)
  bf16* Wb = (bf16*)(ws + (size_t)64  * (1u << 20));   // 32 MiB shared W buffer
  bf16* Qb = (bf16*)(ws + (size_t)96  * (1u << 20));   // 64 MiB
  bf16* Kb = (bf16*)(ws + (size_t)160 * (1u << 20));   // 64 MiB
  bf16* Vb = (bf16*)(ws + (size_t)224 * (1u << 20));   // 64 MiB  (total 288 MiB)

  const int LDS_BYTES = 3 * 24576;                     // 73728
  hipFuncSetAttribute(reinterpret_cast<const void*>(&gemm128x256<bf16, false>),
                      hipFuncAttributeMaxDynamicSharedMemorySize, LDS_BYTES);
  hipFuncSetAttribute(reinterpret_cast<const void*>(&gemm128x256<bf16, true>),
                      hipFuncAttributeMaxDynamicSharedMemorySize, LDS_BYTES);
  hipFuncSetAttribute(reinterpret_cast<const void*>(&gemm128x256<float, false>),
                      hipFuncAttributeMaxDynamicSharedMemorySize, LDS_BYTES);

  const dim3 blk(256);
  const dim3 blk512(512);
  const dim3 cgrid(2048);
  const dim3 ggrid((M / 128) * (N / 256));             // 64*16 = 1024 blocks

  cast_f32_to_bf16<<<cgrid, blk, 0, stream>>>(X, Xb, M * Kd);

  cast_f32_to_bf16<<<cgrid, blk, 0, stream>>>(Wq, Wb, N * Kd);
  gemm128x256<bf16, false><<<ggrid, blk512, LDS_BYTES, stream>>>(Xb, Wb, Qb, M, N, Kd,
      nullptr, nullptr, nullptr, nullptr, nullptr, nullptr);

  cast_f32_to_bf16<<<cgrid, blk, 0, stream>>>(Wk, Wb, N * Kd);
  gemm128x256<bf16, true><<<ggrid, blk512, LDS_BYTES, stream>>>(Xb, Wb, Kb, M, N, Kd,
      mu_q, sigma_q, eps_q, mu_kv, sigma_kv, eps_kv);

  cast_f32_to_bf16<<<cgrid, blk, 0, stream>>>(Wv, Wb, N * Kd);
  gemm128x256<bf16, false><<<ggrid, blk512, LDS_BYTES, stream>>>(Xb, Wb, Vb, M, N, Kd,
      nullptr, nullptr, nullptr, nullptr, nullptr, nullptr);

  bf16* AO = Xb;  // X no longer needed
  attn_mfma<<<dim3(M), blk, 0, stream>>>(Qb, Kb, Vb, mu_kv, sigma_kv, eps_kv, AO);

  cast_f32_to_bf16<<<cgrid, blk, 0, stream>>>(Wo, Wb, N * Kd);
  gemm128x256<float, false><<<ggrid, blk512, LDS_BYTES, stream>>>(AO, Wb, out, M, N, Kd,
      nullptr, nullptr, nullptr, nullptr, nullptr, nullptr);
}

// Round 14
// 1071.113 us; speedup vs baseline: 1.1991x; 1.1991x over previous
//
#include <hip/hip_runtime.h>
#include <hip/hip_bf16.h>

using bf16 = __hip_bfloat16;
typedef __attribute__((ext_vector_type(8))) short short8;
typedef __attribute__((ext_vector_type(4))) float f32x4;

#define GAS(p) ((const __attribute__((address_space(1))) unsigned int*)(p))
#define LAS(p) ((__attribute__((address_space(3))) unsigned int*)(p))

// ---------------- cast f32 -> bf16 (vectorized) ----------------
__global__ __launch_bounds__(256)
void cast_f32_to_bf16(const float* __restrict__ in, bf16* __restrict__ out, int n) {
  const int stride = gridDim.x * blockDim.x * 4;
  for (int i = (blockIdx.x * blockDim.x + threadIdx.x) * 4; i < n; i += stride) {
    float4 v = *reinterpret_cast<const float4*>(in + i);
    bf16 b0 = __float2bfloat16(v.x);
    bf16 b1 = __float2bfloat16(v.y);
    bf16 b2 = __float2bfloat16(v.z);
    bf16 b3 = __float2bfloat16(v.w);
    ushort4 p;
    p.x = *reinterpret_cast<unsigned short*>(&b0);
    p.y = *reinterpret_cast<unsigned short*>(&b1);
    p.z = *reinterpret_cast<unsigned short*>(&b2);
    p.w = *reinterpret_cast<unsigned short*>(&b3);
    *reinterpret_cast<ushort4*>(out + i) = p;
  }
}

// ================= 256x256 deep-pipelined NT GEMM (R12 champion) ============
// R14 change (ONLY): XCD->tile map gives each XCD 2 column-panels so its B
// working set (2 x 2MB) is L2-resident; A-tiles reused by adjacent local ids.
//   xcd = bid&7; local = bid>>3; tn = xcd*2 + (local&1); tm = local>>1.
// Bijective for M/256=32, N/256=16, grid 512 (enumerated).
template <typename OutT, bool KMASK>
__global__ __launch_bounds__(512, 2)
void gemm256(const bf16* __restrict__ A, const bf16* __restrict__ B,
             OutT* __restrict__ C, int M, int N, int K,
             const float* __restrict__ mu_q, const float* __restrict__ sigma_q,
             const float* __restrict__ eps_q,
             const float* __restrict__ mu_kv, const float* __restrict__ sigma_kv,
             const float* __restrict__ eps_kv) {
  extern __shared__ char smem[];   // [0,64K): A bufs, [64K,128K): B bufs

  // B-panel-resident XCD mapping (see header)
  const int bid = blockIdx.x;
  const int xcd = bid & 7;
  const int local = bid >> 3;
  const int tn = xcd * 2 + (local & 1);
  const int tm = local >> 1;
  const int row0 = tm << 8, col0 = tn << 8;

  const int t = threadIdx.x;
  const int wave = t >> 6, lane = t & 63;
  const int wm = wave >> 2, wn = wave & 3;   // 2 x 4 wave grid
  const int fl = lane & 15, g4 = lane >> 4;
  const int ldsWave = wave << 10;            // wave*1024 (stage dest slice)

  // ---- stage-side per-thread source offsets (inverse swizzle, in elems) ----
  const int srow = t >> 3;                                  // 0..63
  const int scol = ((t & 7) * 8) ^
                   (((srow & 2) << 4) | ((srow & 4) << 2) | (srow & 8));
  size_t aRow[2][2], bRow[2][2];                            // [group][issue j]
#pragma unroll
  for (int q = 0; q < 2; ++q)
#pragma unroll
    for (int j = 0; j < 2; ++j) {
      aRow[q][j] = (size_t)(row0 + j * 128 + q * 64 + srow) * K + scol;
      bRow[q][j] = (size_t)(col0 + (j * 2 + (t >> 8)) * 64 + q * 32 +
                            ((t >> 3) & 31)) * K + scol;
    }

  // ---- ds_read byte offsets within a 16KB group region (same swizzle) ----
  int aoff[4][2], boff[2][2];
#pragma unroll
  for (int m = 0; m < 4; ++m) {
    const int lr = wm * 64 + m * 16 + fl;
    const int x = ((lr & 2) << 5) | ((lr & 4) << 3) | ((lr & 8) << 1);
    aoff[m][0] = lr * 128 + ((g4 * 16) ^ x);
    aoff[m][1] = lr * 128 + ((64 + g4 * 16) ^ x);
  }
#pragma unroll
  for (int n = 0; n < 2; ++n) {
    const int lr = wn * 32 + n * 16 + fl;
    const int x = ((lr & 2) << 5) | ((lr & 4) << 3) | ((lr & 8) << 1);
    boff[n][0] = lr * 128 + ((g4 * 16) ^ x);
    boff[n][1] = lr * 128 + ((64 + g4 * 16) ^ x);
  }

  f32x4 acc[8][4];
#pragma unroll
  for (int m = 0; m < 8; ++m)
#pragma unroll
    for (int n = 0; n < 4; ++n) acc[m][n] = (f32x4)0.f;

#define STG_A(buf_, q_, kk_) do {                                             \
    __builtin_amdgcn_global_load_lds(GAS(A + aRow[q_][0] + (kk_)),            \
        LAS(smem + (buf_) * 32768 + (q_) * 16384 + ldsWave), 16, 0, 0);       \
    __builtin_amdgcn_global_load_lds(GAS(A + aRow[q_][1] + (kk_)),            \
        LAS(smem + (buf_) * 32768 + (q_) * 16384 + 8192 + ldsWave), 16, 0, 0);\
  } while (0)
#define STG_B(buf_, q_, kk_) do {                                             \
    __builtin_amdgcn_global_load_lds(GAS(B + bRow[q_][0] + (kk_)),            \
        LAS(smem + 65536 + (buf_) * 32768 + (q_) * 16384 + ldsWave), 16, 0, 0);\
    __builtin_amdgcn_global_load_lds(GAS(B + bRow[q_][1] + (kk_)),            \
        LAS(smem + 65536 + (buf_) * 32768 + (q_) * 16384 + 8192 + ldsWave),   \
        16, 0, 0);                                                            \
  } while (0)

  const int NT = K >> 6;
  // prologue: tile 0 groups in first-use order
  STG_A(0, 0, 0); STG_B(0, 0, 0); STG_B(0, 1, 0); STG_A(0, 1, 0);

  short8 afA[4][2], afB[4][2], bfq0[2][2], bfq1[2][2];

  // validate A0(0),B0(0); pre-read P0's fragments
  asm volatile("s_waitcnt vmcnt(4)" ::: "memory");
  __builtin_amdgcn_s_barrier();
  asm volatile("" ::: "memory");
  {
    const char* As0 = smem;
    const char* Bs0 = smem + 65536;
#pragma unroll
    for (int m = 0; m < 4; ++m) {
      afA[m][0] = *reinterpret_cast<const short8*>(As0 + aoff[m][0]);
      afA[m][1] = *reinterpret_cast<const short8*>(As0 + aoff[m][1]);
    }
#pragma unroll
    for (int n = 0; n < 2; ++n) {
      bfq0[n][0] = *reinterpret_cast<const short8*>(Bs0 + boff[n][0]);
      bfq0[n][1] = *reinterpret_cast<const short8*>(Bs0 + boff[n][1]);
    }
  }

  for (int tt = 0; tt < NT; ++tt) {
    const int cur = tt & 1, nxt = cur ^ 1;
    const size_t kk = (size_t)((tt + 1 < NT) ? ((tt + 1) << 6) : 0);
    const char* As1c = smem + cur * 32768 + 16384;
    const char* Bs1c = smem + 65536 + cur * 32768 + 16384;
    const char* As0n = smem + nxt * 32768;
    const char* Bs0n = smem + 65536 + nxt * 32768;

    // ---- P0: MFMA afA x bfq0 -> acc[0..3][0..1]; read bfq1 <- Bs1(cur) ----
    asm volatile("s_waitcnt vmcnt(2)" ::: "memory");   // B1(t) arrived
    __builtin_amdgcn_s_barrier();
    asm volatile("" ::: "memory");
    STG_A(nxt, 0, kk);
#pragma unroll
    for (int n = 0; n < 2; ++n) {
      bfq1[n][0] = *reinterpret_cast<const short8*>(Bs1c + boff[n][0]);
      bfq1[n][1] = *reinterpret_cast<const short8*>(Bs1c + boff[n][1]);
    }
    __builtin_amdgcn_s_setprio(1);
#pragma unroll
    for (int m = 0; m < 4; ++m)
#pragma unroll
      for (int n = 0; n < 2; ++n) {
        acc[m][n] = __builtin_amdgcn_mfma_f32_16x16x32_bf16(afA[m][0], bfq0[n][0], acc[m][n], 0, 0, 0);
        acc[m][n] = __builtin_amdgcn_mfma_f32_16x16x32_bf16(afA[m][1], bfq0[n][1], acc[m][n], 0, 0, 0);
      }
    __builtin_amdgcn_s_setprio(0);

    // ---- P1: MFMA afA x bfq1 -> acc[0..3][2..3]; read afB <- As1(cur) ----
    asm volatile("s_waitcnt vmcnt(2)" ::: "memory");   // A1(t) arrived
    __builtin_amdgcn_s_barrier();
    asm volatile("" ::: "memory");
    STG_B(nxt, 0, kk);
#pragma unroll
    for (int m = 0; m < 4; ++m) {
      afB[m][0] = *reinterpret_cast<const short8*>(As1c + aoff[m][0]);
      afB[m][1] = *reinterpret_cast<const short8*>(As1c + aoff[m][1]);
    }
    __builtin_amdgcn_s_setprio(1);
#pragma unroll
    for (int m = 0; m < 4; ++m)
#pragma unroll
      for (int n = 0; n < 2; ++n) {
        acc[m][2 + n] = __builtin_amdgcn_mfma_f32_16x16x32_bf16(afA[m][0], bfq1[n][0], acc[m][2 + n], 0, 0, 0);
        acc[m][2 + n] = __builtin_amdgcn_mfma_f32_16x16x32_bf16(afA[m][1], bfq1[n][1], acc[m][2 + n], 0, 0, 0);
      }
    __builtin_amdgcn_s_setprio(0);

    // ---- P2: MFMA afB x bfq0 -> acc[4..7][0..1]; no wait, no reads ----
    STG_B(nxt, 1, kk);
    __builtin_amdgcn_s_setprio(1);
#pragma unroll
    for (int m = 0; m < 4; ++m)
#pragma unroll
      for (int n = 0; n < 2; ++n) {
        acc[4 + m][n] = __builtin_amdgcn_mfma_f32_16x16x32_bf16(afB[m][0], bfq0[n][0], acc[4 + m][n], 0, 0, 0);
        acc[4 + m][n] = __builtin_amdgcn_mfma_f32_16x16x32_bf16(afB[m][1], bfq0[n][1], acc[4 + m][n], 0, 0, 0);
      }
    __builtin_amdgcn_s_setprio(0);

    // ---- P3: MFMA afB x bfq1 -> acc[4..7][2..3]; read afA,bfq0 <- buf(nxt) ----
    asm volatile("s_waitcnt vmcnt(2)" ::: "memory");   // A0(t+1),B0(t+1) arrived
    __builtin_amdgcn_s_barrier();
    asm volatile("" ::: "memory");
    STG_A(nxt, 1, kk);
#pragma unroll
    for (int m = 0; m < 4; ++m) {
      afA[m][0] = *reinterpret_cast<const short8*>(As0n + aoff[m][0]);
      afA[m][1] = *reinterpret_cast<const short8*>(As0n + aoff[m][1]);
    }
#pragma unroll
    for (int n = 0; n < 2; ++n) {
      bfq0[n][0] = *reinterpret_cast<const short8*>(Bs0n + boff[n][0]);
      bfq0[n][1] = *reinterpret_cast<const short8*>(Bs0n + boff[n][1]);
    }
    __builtin_amdgcn_s_setprio(1);
#pragma unroll
    for (int m = 0; m < 4; ++m)
#pragma unroll
      for (int n = 0; n < 2; ++n) {
        acc[4 + m][2 + n] = __builtin_amdgcn_mfma_f32_16x16x32_bf16(afB[m][0], bfq1[n][0], acc[4 + m][2 + n], 0, 0, 0);
        acc[4 + m][2 + n] = __builtin_amdgcn_mfma_f32_16x16x32_bf16(afB[m][1], bfq1[n][1], acc[4 + m][2 + n], 0, 0, 0);
      }
    __builtin_amdgcn_s_setprio(0);
  }
#undef STG_A
#undef STG_B

  asm volatile("s_waitcnt vmcnt(0)" ::: "memory");

  // ---- epilogue: C/D layout col=lane&15, row=(lane>>4)*4+reg ----
  const int crow0 = row0 + wm * 128 + g4 * 4;
  const int ccol0 = col0 + wn * 64 + fl;
  float cscale[4];
  if constexpr (KMASK) {
#pragma unroll
    for (int n = 0; n < 4; ++n) {
      const int d = (ccol0 + n * 16) & 63;
      const float a = mu_q[d] + eps_q[d] * sigma_q[d];
      const float b = mu_kv[d] + eps_kv[d] * sigma_kv[d];
      cscale[n] = 0.125f / ((1.f + __expf(-a)) * (1.f + __expf(-b)));
    }
  }
#pragma unroll
  for (int m = 0; m < 8; ++m) {
#pragma unroll
    for (int n = 0; n < 4; ++n) {
      const int cc = ccol0 + n * 16;
#pragma unroll
      for (int r = 0; r < 4; ++r) {
        const int rr = crow0 + m * 16 + r;
        float v = acc[m][n][r];
        if constexpr (KMASK) v *= cscale[n];
        if constexpr (sizeof(OutT) == 2) {
          C[(size_t)rr * N + cc] = __float2bfloat16(v);
        } else {
          C[(size_t)rr * N + cc] = v;
        }
      }
    }
  }
}

// ---------------- per-token cross-head attention, MFMA ----------------
__global__ __launch_bounds__(256)
void attn_mfma(const bf16* __restrict__ Q, const bf16* __restrict__ K,
               const bf16* __restrict__ V,
               const float* __restrict__ mu_kv, const float* __restrict__ sigma_kv,
               const float* __restrict__ eps_kv,
               bf16* __restrict__ AO) {
  __shared__ bf16 Vt[64][72];
  __shared__ bf16 P[4][16][72];

  const int t = threadIdx.x;
  const int wave = t >> 6, lane = t & 63;
  const int fl = lane & 15, g4 = lane >> 4;
  const int kq = g4 * 8;
  const size_t base = (size_t)blockIdx.x * 4096;

#pragma unroll
  for (int rep = 0; rep < 2; ++rep) {
    const int idx = rep * 256 + t;
    const int g = idx & 63;
    const int d0 = (idx >> 6) * 8;
    short8 v8 = *reinterpret_cast<const short8*>(&V[base + (size_t)g * 64 + d0]);
#pragma unroll
    for (int j = 0; j < 8; ++j)
      *reinterpret_cast<short*>(&Vt[d0 + j][g]) = (short)v8[j];
  }

  short8 aq[2];
#pragma unroll
  for (int ks = 0; ks < 2; ++ks)
    aq[ks] = *reinterpret_cast<const short8*>(
        &Q[base + (size_t)(wave * 16 + fl) * 64 + ks * 32 + kq]);
  short8 bk[4][2];
#pragma unroll
  for (int n = 0; n < 4; ++n)
#pragma unroll
    for (int ks = 0; ks < 2; ++ks)
      bk[n][ks] = *reinterpret_cast<const short8*>(
          &K[base + (size_t)(n * 16 + fl) * 64 + ks * 32 + kq]);

  f32x4 sacc[4];
#pragma unroll
  for (int n = 0; n < 4; ++n) sacc[n] = (f32x4)0.f;
#pragma unroll
  for (int n = 0; n < 4; ++n)
#pragma unroll
    for (int ks = 0; ks < 2; ++ks)
      sacc[n] = __builtin_amdgcn_mfma_f32_16x16x32_bf16(aq[ks], bk[n][ks],
                                                        sacc[n], 0, 0, 0);

  float recip[4];
  float ex[4][4];
#pragma unroll
  for (int r = 0; r < 4; ++r) {
    float mx = fmaxf(fmaxf(sacc[0][r], sacc[1][r]), fmaxf(sacc[2][r], sacc[3][r]));
    mx = fmaxf(mx, __shfl_xor(mx, 1, 64));
    mx = fmaxf(mx, __shfl_xor(mx, 2, 64));
    mx = fmaxf(mx, __shfl_xor(mx, 4, 64));
    mx = fmaxf(mx, __shfl_xor(mx, 8, 64));
    float sum = 0.f;
#pragma unroll
    for (int n = 0; n < 4; ++n) {
      ex[n][r] = __expf(sacc[n][r] - mx);
      sum += ex[n][r];
    }
    sum += __shfl_xor(sum, 1, 64);
    sum += __shfl_xor(sum, 2, 64);
    sum += __shfl_xor(sum, 4, 64);
    sum += __shfl_xor(sum, 8, 64);
    recip[r] = 1.f / sum;
  }

#pragma unroll
  for (int n = 0; n < 4; ++n)
#pragma unroll
    for (int r = 0; r < 4; ++r)
      P[wave][g4 * 4 + r][n * 16 + fl] = __float2bfloat16(ex[n][r]);

  __syncthreads();

  short8 ap[2];
#pragma unroll
  for (int ks = 0; ks < 2; ++ks)
    ap[ks] = *reinterpret_cast<const short8*>(&P[wave][fl][ks * 32 + kq]);
  short8 bv[4][2];
#pragma unroll
  for (int n = 0; n < 4; ++n)
#pragma unroll
    for (int ks = 0; ks < 2; ++ks)
      bv[n][ks] = *reinterpret_cast<const short8*>(&Vt[n * 16 + fl][ks * 32 + kq]);

  f32x4 oacc[4];
#pragma unroll
  for (int n = 0; n < 4; ++n) oacc[n] = (f32x4)0.f;
#pragma unroll
  for (int n = 0; n < 4; ++n)
#pragma unroll
    for (int ks = 0; ks < 2; ++ks)
      oacc[n] = __builtin_amdgcn_mfma_f32_16x16x32_bf16(ap[ks], bv[n][ks],
                                                        oacc[n], 0, 0, 0);

  float mkvc[4];
#pragma unroll
  for (int n = 0; n < 4; ++n) {
    const int d = n * 16 + fl;
    mkvc[n] = 1.f / (1.f + __expf(-(mu_kv[d] + eps_kv[d] * sigma_kv[d])));
  }
#pragma unroll
  for (int n = 0; n < 4; ++n) {
    const int d = n * 16 + fl;
#pragma unroll
    for (int r = 0; r < 4; ++r) {
      const int h = wave * 16 + g4 * 4 + r;
      AO[base + (size_t)h * 64 + d] =
          __float2bfloat16(oacc[n][r] * recip[r] * mkvc[n]);
    }
  }
}

// ---------------- launch ----------------
extern "C" void kernel_launch(void* const* d_in, const int* in_sizes, int n_in,
                              void* d_out, int out_size, void* d_ws, size_t ws_size,
                              hipStream_t stream) {
  (void)in_sizes; (void)n_in; (void)out_size; (void)ws_size;
  const float* X        = (const float*)d_in[0];
  const float* Wq       = (const float*)d_in[1];
  const float* Wk       = (const float*)d_in[2];
  const float* Wv       = (const float*)d_in[3];
  const float* Wo       = (const float*)d_in[4];
  const float* mu_q     = (const float*)d_in[5];
  const float* sigma_q  = (const float*)d_in[6];
  const float* mu_kv    = (const float*)d_in[7];
  const float* sigma_kv = (const float*)d_in[8];
  const float* eps_q    = (const float*)d_in[9];
  const float* eps_kv   = (const float*)d_in[10];
  float* out = (float*)d_out;

  const int M = 8192, N = 4096, Kd = 4096;

  char* ws = (char*)d_ws;
  bf16* Xb = (bf16*)(ws);                              // 64 MiB (reused as AO)
  bf16* Wb = (bf16*)(ws + (size_t)64  * (1u << 20));   // 32 MiB shared W buffer
  bf16* Qb = (bf16*)(ws + (size_t)96  * (1u << 20));   // 64 MiB
  bf16* Kb = (bf16*)(ws + (size_t)160 * (1u << 20));   // 64 MiB
  bf16* Vb = (bf16*)(ws + (size_t)224 * (1u << 20));   // 64 MiB  (total 288 MiB)

  const int LDS_BYTES = 131072;
  hipFuncSetAttribute(reinterpret_cast<const void*>(&gemm256<bf16, false>),
                      hipFuncAttributeMaxDynamicSharedMemorySize, LDS_BYTES);
  hipFuncSetAttribute(reinterpret_cast<const void*>(&gemm256<bf16, true>),
                      hipFuncAttributeMaxDynamicSharedMemorySize, LDS_BYTES);
  hipFuncSetAttribute(reinterpret_cast<const void*>(&gemm256<float, false>),
                      hipFuncAttributeMaxDynamicSharedMemorySize, LDS_BYTES);

  const dim3 blk(256);
  const dim3 blk512(512);
  const dim3 cgrid(2048);
  const dim3 ggrid((M / 256) * (N / 256));             // 512 blocks

  cast_f32_to_bf16<<<cgrid, blk, 0, stream>>>(X, Xb, M * Kd);

  cast_f32_to_bf16<<<cgrid, blk, 0, stream>>>(Wq, Wb, N * Kd);
  gemm256<bf16, false><<<ggrid, blk512, LDS_BYTES, stream>>>(Xb, Wb, Qb, M, N, Kd,
      nullptr, nullptr, nullptr, nullptr, nullptr, nullptr);

  cast_f32_to_bf16<<<cgrid, blk, 0, stream>>>(Wk, Wb, N * Kd);
  gemm256<bf16, true><<<ggrid, blk512, LDS_BYTES, stream>>>(Xb, Wb, Kb, M, N, Kd,
      mu_q, sigma_q, eps_q, mu_kv, sigma_kv, eps_kv);

  cast_f32_to_bf16<<<cgrid, blk, 0, stream>>>(Wv, Wb, N * Kd);
  gemm256<bf16, false><<<ggrid, blk512, LDS_BYTES, stream>>>(Xb, Wb, Vb, M, N, Kd,
      nullptr, nullptr, nullptr, nullptr, nullptr, nullptr);

  bf16* AO = Xb;  // X no longer needed
  attn_mfma<<<dim3(M), blk, 0, stream>>>(Qb, Kb, Vb, mu_kv, sigma_kv, eps_kv, AO);

  cast_f32_to_bf16<<<cgrid, blk, 0, stream>>>(Wo, Wb, N * Kd);
  gemm256<float, false><<<ggrid, blk512, LDS_BYTES, stream>>>(AO, Wb, out, M, N, Kd,
      nullptr, nullptr, nullptr, nullptr, nullptr, nullptr);
}